// Round 2
// baseline (118.629 us; speedup 1.0000x reference)
//
#include <hip/hip_runtime.h>

#define NPT 384
#define NB 2
#define HOFF 49152   // NB*NPT*64, start of x section in d_out

typedef unsigned short u16;
typedef unsigned int u32;
typedef __bf16 bf16x8 __attribute__((ext_vector_type(8)));
typedef float f32x4 __attribute__((ext_vector_type(4)));

struct alignas(16) U4 { u32 x, y, z, w; };

constexpr float kEPS = 1e-5f;
constexpr float kINF = 1e5f;

__device__ __forceinline__ u16 f2b(float f) {            // f32 -> bf16 bits, RNE
  u32 x = __float_as_uint(f);
  x += 0x7fffu + ((x >> 16) & 1u);
  return (u16)(x >> 16);
}
__device__ __forceinline__ float b2f(u32 u) { return __uint_as_float(u << 16); }
__device__ __forceinline__ float silu_f(float v) { return v / (1.f + __expf(-v)); }
__device__ __forceinline__ float wredmax(float v) {
#pragma unroll
  for (int m = 32; m >= 1; m >>= 1) v = fmaxf(v, __shfl_xor(v, m, 64));
  return v;
}
__device__ __forceinline__ float wredsum(float v) {
#pragma unroll
  for (int m = 32; m >= 1; m >>= 1) v += __shfl_xor(v, m, 64);
  return v;
}
__device__ __forceinline__ void up8(U4 u, float* f) {
  f[0] = b2f(u.x & 0xffffu); f[1] = b2f(u.x >> 16);
  f[2] = b2f(u.y & 0xffffu); f[3] = b2f(u.y >> 16);
  f[4] = b2f(u.z & 0xffffu); f[5] = b2f(u.z >> 16);
  f[6] = b2f(u.w & 0xffffu); f[7] = b2f(u.w >> 16);
}

// ---------------- prep: U = h@We0[:64]+be0, V = h@We0[64:128]; bf16 transposed weight images ----------------
__global__ __launch_bounds__(64) void sake_prep(
    const float* __restrict__ h, const float* __restrict__ We0,
    const float* __restrict__ be0, const float* __restrict__ We1,
    const float* __restrict__ Wc0, const float* __restrict__ Wc1,
    const float* __restrict__ Wx0, const float* __restrict__ Ws,
    float* __restrict__ U, float* __restrict__ V, u16* __restrict__ WT)
{
  const int t = threadIdx.x;
  const int blk = blockIdx.x;
  if (blk < NB * NPT) {
    __shared__ float hs[64];
    hs[t] = h[blk * 64 + t];
    __syncthreads();
    float u = be0[t], v = 0.f;
#pragma unroll 8
    for (int k = 0; k < 64; k++) {
      float hv = hs[k];
      u = fmaf(hv, We0[k * 64 + t], u);
      v = fmaf(hv, We0[(64 + k) * 64 + t], v);
    }
    U[blk * 64 + t] = u;
    V[blk * 64 + t] = v;
  } else {
    // transposed bf16 images: WT[n][k] = W[k][n]
    const int wsel = blk - NB * NPT;
    if (wsel == 4) {
      // WsPT: 16x64, cols 4..15 zero-padded
      u16* dst = WT + 14336;
      for (int o = t; o < 16 * 64; o += 64) {
        int c = o >> 6, k = o & 63;
        dst[o] = (c < 4) ? f2b(Ws[k * 4 + c]) : (u16)0;
      }
      return;
    }
    const float* src; int nout; u16* dst;
    if      (wsel == 0) { src = We1; nout = 64; dst = WT;         }
    else if (wsel == 1) { src = Wc0; nout = 64; dst = WT + 4096;  }
    else if (wsel == 2) { src = Wx0; nout = 64; dst = WT + 8192;  }
    else                { src = Wc1; nout = 32; dst = WT + 12288; }
    const int total = 64 * nout;
    for (int o = t; o < total; o += 64) {
      int n = o >> 6, k = o & 63;
      dst[o] = f2b(src[k * nout + n]);
    }
  }
}

// ---------------- main ----------------
struct MainArgs {
  const float *h, *x, *U, *V;
  const u16 *We1T, *Wc0T, *Wx0T, *Wc1T, *WsPT;
  const float *We0, *bs, *be1, *bc0, *bc1, *bx0, *Wx1, *log_gamma;
  const float *Wp0, *bp0, *Wp1, *bp1, *Wn0, *bn0, *Wn1, *bn1;
  float* out;
};

// 64x64 @ 64x64 GEMM (A: swizzled bf16 LDS tile, B: global [n][k] bf16 image), silu, out swizzled bf16 LDS.
// wave w owns rows 16w..16w+15. Row-major swizzle: 16B chunk c of row r stored at chunk (c ^ (r&7)).
// DUALT also writes transposed copy oTT[col][row], swizzled: elem (c,k) at c*64 + (((k>>3)^(c&7))<<3) + (k&7).
template<bool DUALT>
__device__ __forceinline__ void gemm64(const u16* aT, const u16* __restrict__ wG,
                                       const float* bias, u16* oT, u16* oTT, int w, int lane)
{
  const int m0 = w << 4;
  const int arow = m0 + (lane & 15);
  const int r7 = arow & 7;
  const int kg = lane >> 4;
  bf16x8 a0 = *(const bf16x8*)(aT + arow * 64 + ((kg ^ r7) << 3));
  bf16x8 a1 = *(const bf16x8*)(aT + arow * 64 + ((((kg + 4)) ^ r7) << 3));
#pragma unroll
  for (int nt = 0; nt < 4; nt++) {
    const int col = (nt << 4) + (lane & 15);
    const u16* wrow = wG + col * 64;
    bf16x8 b0 = *(const bf16x8*)(wrow + (kg << 3));
    bf16x8 b1 = *(const bf16x8*)(wrow + 32 + (kg << 3));
    f32x4 acc = {0.f, 0.f, 0.f, 0.f};
    acc = __builtin_amdgcn_mfma_f32_16x16x32_bf16(a0, b0, acc, 0, 0, 0);
    acc = __builtin_amdgcn_mfma_f32_16x16x32_bf16(a1, b1, acc, 0, 0, 0);
    const float bv = bias[col];
    const int cs = col >> 3, ce = col & 7;
#pragma unroll
    for (int r = 0; r < 4; r++) {
      const int row = m0 + (kg << 2) + r;
      const u16 v = f2b(silu_f(acc[r] + bv));
      oT[row * 64 + ((cs ^ (row & 7)) << 3) + ce] = v;
      if constexpr (DUALT)
        oTT[col * 64 + ((((row >> 3)) ^ (col & 7)) << 3) + (row & 7)] = v;
    }
  }
}

__global__ __launch_bounds__(256, 3) void sake_main(MainArgs A)
{
  __shared__ __align__(16) u16 buf0[64 * 64];   // h1 / c1 / s1
  __shared__ __align__(16) u16 hes[64 * 64];    // h_e row-major swizzled
  __shared__ __align__(16) u16 hesT[64 * 64];   // h_e transposed swizzled
  __shared__ __align__(16) u16 E_lds[16 * 64];  // eL tile (rows 4..15 zero)
  __shared__ __align__(16) u16 coeff[64 * 34];  // coeff bf16 (also finalize scratch)
  __shared__ float raw_lds[64 * 5];             // sem logits [j][head], padded
  __shared__ float disp[64][3];
  __shared__ float nrm_s[64];                   // also reused as comb_norm[32]
  __shared__ float invn_s[64];
  __shared__ float sU[64], wd[64], sbe1[64], sbc0[64], sbx0[64], sWx1[64];
  __shared__ float sbc1[32], sbs[4], sgam[4], xi_s[3];
  __shared__ float facL_s[4], coefh_s[4];
  __shared__ float node_in[384];
  __shared__ float t0s[64];
  __shared__ float cmv[96];

  const int t = threadIdx.x;
  const int w = t >> 6, lane = t & 63;
  const int bi = blockIdx.x;
  const int b = bi / NPT, i = bi - b * NPT;
  const int jj2 = t >> 2, q4 = t & 3;

  if (t < 64) {
    sU[t]   = A.U[bi * 64 + t];
    wd[t]   = A.We0[128 * 64 + t];
    sbe1[t] = A.be1[t];
    sbc0[t] = A.bc0[t];
    sbx0[t] = A.bx0[t];
    sWx1[t] = A.Wx1[t];
    if (t < 32) sbc1[t] = A.bc1[t];
    if (t < 4) { sbs[t] = A.bs[t]; sgam[t] = __expf(A.log_gamma[t]); }
    if (t < 3) xi_s[t] = A.x[(b * NPT + i) * 3 + t];
  }
  ((u32*)E_lds)[t] = 0; ((u32*)E_lds)[256 + t] = 0;   // zero E tile (rows 4..15 stay 0)
  __syncthreads();

  // state; head = wave. aFrag = MFMA C/D fragment of A[head][f], wave w owns cols 16w..16w+15.
  f32x4 aFrag = {0.f, 0.f, 0.f, 0.f};
  float mL = -1e30f, SL = 0.f, mb = -1e30f, Sb = 0.f, saPart = 0.f;
  float cA0 = 0, cA1 = 0, cA2 = 0, xA0 = 0, xA1 = 0, xA2 = 0;

  for (int jt = 0; jt < 6; ++jt) {
    const int j0 = jt << 6;
    __syncthreads();  // barrier 1: previous tile fully consumed

    // ---- stage h1 = silu(u_i + v_j + norm*wd) (wave-local rows 16w..16w+15) ----
    {
      const int j = j0 + jj2;
      const float* xp = &A.x[(b * NPT + j) * 3];
      float dx0 = xi_s[0] - xp[0], dx1 = xi_s[1] - xp[1], dx2 = xi_s[2] - xp[2];
      float nr = sqrtf(fmaf(dx0, dx0, fmaf(dx1, dx1, fmaf(dx2, dx2, kEPS))));
      if (q4 == 0) {
        disp[jj2][0] = dx0; disp[jj2][1] = dx1; disp[jj2][2] = dx2;
        nrm_s[jj2] = nr; invn_s[jj2] = 1.f / (nr + kEPS);
      }
      const float4* vp = (const float4*)(A.V + (size_t)(b * NPT + j) * 64 + q4 * 16);
      float4 v0_ = vp[0], v1_ = vp[1], v2_ = vp[2], v3_ = vp[3];
      float vv[16] = {v0_.x, v0_.y, v0_.z, v0_.w, v1_.x, v1_.y, v1_.z, v1_.w,
                      v2_.x, v2_.y, v2_.z, v2_.w, v3_.x, v3_.y, v3_.z, v3_.w};
      u16 pk[16];
#pragma unroll
      for (int e = 0; e < 16; e++) {
        const int f = q4 * 16 + e;
        pk[e] = f2b(silu_f(sU[f] + vv[e] + nr * wd[f]));
      }
      U4 lo, hi;
      lo.x = pk[0] | ((u32)pk[1] << 16);  lo.y = pk[2] | ((u32)pk[3] << 16);
      lo.z = pk[4] | ((u32)pk[5] << 16);  lo.w = pk[6] | ((u32)pk[7] << 16);
      hi.x = pk[8] | ((u32)pk[9] << 16);  hi.y = pk[10] | ((u32)pk[11] << 16);
      hi.z = pk[12] | ((u32)pk[13] << 16); hi.w = pk[14] | ((u32)pk[15] << 16);
      const int r7 = jj2 & 7;
      *(U4*)(buf0 + jj2 * 64 + (((q4 * 2) ^ r7) << 3)) = lo;
      *(U4*)(buf0 + jj2 * 64 + (((q4 * 2 + 1) ^ r7) << 3)) = hi;
    }
    // ---- h_e = silu(h1 @ We1 + be1), dual write (row-major + transposed) ----
    gemm64<true>(buf0, A.We1T, sbe1, hes, hesT, w, lane);
    __syncthreads();  // barrier 2: hes/hesT complete (cross-wave consumers below)

    // ---- c1 = silu(h_e @ Wc0 + bc0) ----
    gemm64<false>(hes, A.Wc0T, sbc0, buf0, nullptr, w, lane);
    // ---- coeff = c1 @ Wc1 + bc1 ----
    {
      const int m0 = w << 4;
      const int arow = m0 + (lane & 15);
      const int r7a = arow & 7;
      const int kg = lane >> 4;
      bf16x8 a0 = *(const bf16x8*)(buf0 + arow * 64 + ((kg ^ r7a) << 3));
      bf16x8 a1 = *(const bf16x8*)(buf0 + arow * 64 + (((kg + 4) ^ r7a) << 3));
#pragma unroll
      for (int nt = 0; nt < 2; nt++) {
        const int col = (nt << 4) + (lane & 15);
        const u16* wrow = A.Wc1T + col * 64;
        bf16x8 b0 = *(const bf16x8*)(wrow + (kg << 3));
        bf16x8 b1 = *(const bf16x8*)(wrow + 32 + (kg << 3));
        f32x4 acc = {0.f, 0.f, 0.f, 0.f};
        acc = __builtin_amdgcn_mfma_f32_16x16x32_bf16(a0, b0, acc, 0, 0, 0);
        acc = __builtin_amdgcn_mfma_f32_16x16x32_bf16(a1, b1, acc, 0, 0, 0);
        const float bv = sbc1[col];
#pragma unroll
        for (int r = 0; r < 4; r++) {
          const int row = m0 + (kg << 2) + r;
          coeff[row * 34 + col] = f2b(acc[r] + bv);
        }
      }
    }
    // ---- combinations accumulation (mean over j of coeff_c * xhat_d) ----
    {
      const int c = t & 31, g = t >> 5;   // wave-local: g in {2w,2w+1}
#pragma unroll
      for (int it = 0; it < 8; ++it) {
        const int jj = (g << 3) + it;
        const float s = b2f(coeff[jj * 34 + c]) * invn_s[jj];
        cA0 = fmaf(s, disp[jj][0], cA0);
        cA1 = fmaf(s, disp[jj][1], cA1);
        cA2 = fmaf(s, disp[jj][2], cA2);
      }
    }
    // ---- s1 = silu(h_e @ Wx0 + bx0) ----
    gemm64<false>(hes, A.Wx0T, sbx0, buf0, nullptr, w, lane);
    // ---- scale = s1 @ Wx1 ; coordinate accumulation ----
    {
      const int jj = jj2;
      const int r7 = jj & 7;
      float acc = 0.f;
#pragma unroll
      for (int c2 = 0; c2 < 2; c2++) {
        const int c = q4 * 2 + c2;
        U4 u = *(const U4*)(buf0 + jj * 64 + ((c ^ r7) << 3));
        float f8[8]; up8(u, f8);
#pragma unroll
        for (int e = 0; e < 8; e++) acc = fmaf(f8[e], sWx1[c * 8 + e], acc);
      }
      acc += __shfl_xor(acc, 1, 64);
      acc += __shfl_xor(acc, 2, 64);
      if (q4 == 0) {
        xA0 = fmaf(disp[jj][0], acc, xA0);
        xA1 = fmaf(disp[jj][1], acc, xA1);
        xA2 = fmaf(disp[jj][2], acc, xA2);
      }
    }
    // ---- semantic logits via MFMA: raw[j][head] = h_e @ WsP (N padded to 16) ----
    {
      const int m0 = w << 4;
      const int arow = m0 + (lane & 15);
      const int r7a = arow & 7;
      const int kg = lane >> 4;
      bf16x8 a0 = *(const bf16x8*)(hes + arow * 64 + ((kg ^ r7a) << 3));
      bf16x8 a1 = *(const bf16x8*)(hes + arow * 64 + (((kg + 4) ^ r7a) << 3));
      const u16* wrow = A.WsPT + (lane & 15) * 64;
      bf16x8 b0 = *(const bf16x8*)(wrow + (kg << 3));
      bf16x8 b1 = *(const bf16x8*)(wrow + 32 + (kg << 3));
      f32x4 acc = {0.f, 0.f, 0.f, 0.f};
      acc = __builtin_amdgcn_mfma_f32_16x16x32_bf16(a0, b0, acc, 0, 0, 0);
      acc = __builtin_amdgcn_mfma_f32_16x16x32_bf16(a1, b1, acc, 0, 0, 0);
      if ((lane & 15) < 4) {
#pragma unroll
        for (int r = 0; r < 4; r++)
          raw_lds[(m0 + (kg << 2) + r) * 5 + (lane & 15)] = acc[r];
      }
    }
    __syncthreads();  // barrier 3: raw_lds ready (cross-wave read next)

    // ---- online dual softmax (head = w, j = lane); eu max is exactly 0-bounded (aeu<=0) ----
    {
      const int jj = lane, head = w;
      float raw = raw_lds[jj * 5 + head] + sbs[head];
      float bsem = (raw > 0.f) ? raw : 0.2f * raw;           // leaky_relu 0.2
      const bool self = (j0 + jj) == i;
      if (self) bsem -= kINF;
      const float aeu = -(nrm_s[jj] + (self ? kINF : 0.f)) * sgam[head];
      const float L = aeu + bsem;
      const float nmb = fmaxf(mb, wredmax(bsem));
      const float nmL = fmaxf(mL, wredmax(L));
      saPart += __expf(aeu);                                  // deferred Sa (ma == 0)
      const float eB = __expf(bsem - nmb);
      const float eL = __expf(L - nmL);
      Sb = fmaf(Sb, __expf(mb - nmb), wredsum(eB));
      const float facL = __expf(mL - nmL);
      SL = fmaf(SL, facL, wredsum(eL));
      mb = nmb; mL = nmL;
      E_lds[head * 64 + (((jj >> 3) ^ head) << 3) + (jj & 7)] = f2b(eL);
      if (lane == 0) facL_s[head] = facL;
    }
    __syncthreads();  // barrier 4: E_lds + facL ready

    // ---- A-accumulation via MFMA: aFrag = diag-rescale(aFrag) + E @ h_e ----
    {
      const int kg = lane >> 4;
      const int erow = lane & 15;
      const int e7 = erow & 7;
      bf16x8 ea0 = *(const bf16x8*)(E_lds + erow * 64 + ((kg ^ e7) << 3));
      bf16x8 ea1 = *(const bf16x8*)(E_lds + erow * 64 + (((kg + 4) ^ e7) << 3));
      const int f = (w << 4) + (lane & 15);
      const int f7 = f & 7;
      bf16x8 hb0 = *(const bf16x8*)(hesT + f * 64 + ((kg ^ f7) << 3));
      bf16x8 hb1 = *(const bf16x8*)(hesT + f * 64 + (((kg + 4) ^ f7) << 3));
#pragma unroll
      for (int r = 0; r < 4; r++) aFrag[r] *= facL_s[r];   // rows>=4 hold zeros anyway
      aFrag = __builtin_amdgcn_mfma_f32_16x16x32_bf16(ea0, hb0, aFrag, 0, 0, 0);
      aFrag = __builtin_amdgcn_mfma_f32_16x16x32_bf16(ea1, hb1, aFrag, 0, 0, 0);
    }
  }

  // ================= finalize =================
  __syncthreads();
  float* scratch = (float*)coeff;  // 1088 floats
  float* xscr = (float*)hes;
  scratch[t * 3 + 0] = cA0; scratch[t * 3 + 1] = cA1; scratch[t * 3 + 2] = cA2;
  if (q4 == 0) { xscr[jj2 * 3 + 0] = xA0; xscr[jj2 * 3 + 1] = xA1; xscr[jj2 * 3 + 2] = xA2; }
  {
    const float Sa = wredsum(saPart);
    if (lane == 0) {
      const float Ff = __expf(mL - mb);                     // ma == 0
      const float denom = fmaf(SL, Ff, kEPS * Sa * Sb);
      coefh_s[w] = Ff / denom;
    }
  }
  if (t < 64) node_in[t] = A.h[bi * 64 + t];
  __syncthreads();
  if (lane < 16) {
#pragma unroll
    for (int r = 0; r < 4; r++)
      node_in[64 + r * 64 + (w << 4) + lane] = aFrag[r] * coefh_s[r];  // h_e_agg head-major
  }
  if (t < 96) {
    const int c = t & 31, d = t >> 5;
    float s = 0.f;
#pragma unroll
    for (int g = 0; g < 8; g++) s += scratch[(g * 32 + c) * 3 + d];
    cmv[d * 32 + c] = s * (1.f / 384.f);
  }
  if (t >= 128 && t < 131) {
    const int d = t - 128;
    float s = 0.f;
    for (int k = 0; k < 64; k++) s += xscr[k * 3 + d];
    A.out[HOFF + bi * 3 + d] = xi_s[d] + s * (1.f / 384.f);
  }
  __syncthreads();
  if (t < 32) {
    float v0 = cmv[t], v1 = cmv[32 + t], v2 = cmv[64 + t];
    nrm_s[t] = v0 * v0 + v1 * v1 + v2 * v2;   // comb_norm
  }
  __syncthreads();
  if (t < 64) {
    float acc = A.bp0[t];
    for (int c = 0; c < 32; c++) acc = fmaf(nrm_s[c], A.Wp0[c * 64 + t], acc);
    t0s[t] = silu_f(acc);
  }
  __syncthreads();
  if (t < 64) {
    float acc = A.bp1[t];
    for (int k = 0; k < 64; k++) acc = fmaf(t0s[k], A.Wp1[k * 64 + t], acc);
    node_in[320 + t] = acc;   // h_comb
  }
  __syncthreads();
  {
    const int f = t & 63, q = t >> 6;
    float acc = 0.f;
    const int k0 = q * 96;
    for (int k = 0; k < 96; k++) acc = fmaf(node_in[k0 + k], A.Wn0[(k0 + k) * 64 + f], acc);
    scratch[q * 64 + f] = acc;
  }
  __syncthreads();
  if (t < 64) {
    float s = scratch[t] + scratch[64 + t] + scratch[128 + t] + scratch[192 + t] + A.bn0[t];
    t0s[t] = silu_f(s);
  }
  __syncthreads();
  if (t < 64) {
    float acc = A.bn1[t];
    for (int k = 0; k < 64; k++) acc = fmaf(t0s[k], A.Wn1[k * 64 + t], acc);
    A.out[bi * 64 + t] = A.h[bi * 64 + t] + acc;
  }
}

extern "C" void kernel_launch(void* const* d_in, const int* in_sizes, int n_in,
                              void* d_out, int out_size, void* d_ws, size_t ws_size,
                              hipStream_t stream)
{
  (void)in_sizes; (void)n_in; (void)out_size; (void)ws_size;
  const float* h   = (const float*)d_in[0];
  const float* x   = (const float*)d_in[1];
  const float* We0 = (const float*)d_in[2];
  const float* be0 = (const float*)d_in[3];
  const float* We1 = (const float*)d_in[4];
  const float* be1 = (const float*)d_in[5];
  const float* Ws  = (const float*)d_in[6];
  const float* bs  = (const float*)d_in[7];
  const float* Wc0 = (const float*)d_in[8];
  const float* bc0 = (const float*)d_in[9];
  const float* Wc1 = (const float*)d_in[10];
  const float* bc1 = (const float*)d_in[11];
  const float* Wp0 = (const float*)d_in[12];
  const float* bp0 = (const float*)d_in[13];
  const float* Wp1 = (const float*)d_in[14];
  const float* bp1 = (const float*)d_in[15];
  const float* Wx0 = (const float*)d_in[16];
  const float* bx0 = (const float*)d_in[17];
  const float* Wx1 = (const float*)d_in[18];
  const float* Wn0 = (const float*)d_in[19];
  const float* bn0 = (const float*)d_in[20];
  const float* Wn1 = (const float*)d_in[21];
  const float* bn1 = (const float*)d_in[22];
  const float* lg  = (const float*)d_in[23];

  float* U = (float*)d_ws;
  float* V = U + NB * NPT * 64;
  u16* WT = (u16*)(V + NB * NPT * 64);

  sake_prep<<<NB * NPT + 5, 64, 0, stream>>>(h, We0, be0, We1, Wc0, Wc1, Wx0, Ws, U, V, WT);

  MainArgs A;
  A.h = h; A.x = x; A.U = U; A.V = V;
  A.We1T = WT; A.Wc0T = WT + 4096; A.Wx0T = WT + 8192; A.Wc1T = WT + 12288;
  A.WsPT = WT + 14336;
  A.We0 = We0; A.bs = bs; A.be1 = be1; A.bc0 = bc0; A.bc1 = bc1;
  A.bx0 = bx0; A.Wx1 = Wx1; A.log_gamma = lg;
  A.Wp0 = Wp0; A.bp0 = bp0; A.Wp1 = Wp1; A.bp1 = bp1;
  A.Wn0 = Wn0; A.bn0 = bn0; A.Wn1 = Wn1; A.bn1 = bn1;
  A.out = (float*)d_out;

  sake_main<<<NB * NPT, 256, 0, stream>>>(A);
}

// Round 3
// 98.152 us; speedup vs baseline: 1.2086x; 1.2086x over previous
//
#include <hip/hip_runtime.h>

#define NPT 384
#define NB 2
#define NROW (NB*NPT)        // 768
#define NT 6                 // j-tiles per row
#define HOFF 49152           // start of x section in d_out
#define RECB 1024            // bytes per partial record
#define REC_OFF 424960       // byte offset of records in d_ws

typedef unsigned short u16;
typedef unsigned int u32;
typedef __bf16 bf16x8 __attribute__((ext_vector_type(8)));
typedef float f32x4 __attribute__((ext_vector_type(4)));

struct alignas(16) U4 { u32 x, y, z, w; };

constexpr float kEPS = 1e-5f;
constexpr float kINF = 1e5f;

__device__ __forceinline__ u16 f2b(float f) { __bf16 b = (__bf16)f; return __builtin_bit_cast(u16, b); }
__device__ __forceinline__ u32 pk2(float lo, float hi) { return (u32)f2b(lo) | ((u32)f2b(hi) << 16); }
__device__ __forceinline__ float b2f(u32 u) { return __uint_as_float(u << 16); }
__device__ __forceinline__ float silu_f(float v) { return v * __builtin_amdgcn_rcpf(1.f + __expf(-v)); }
__device__ __forceinline__ float wredmax(float v) {
#pragma unroll
  for (int m = 32; m >= 1; m >>= 1) v = fmaxf(v, __shfl_xor(v, m, 64));
  return v;
}
__device__ __forceinline__ float wredsum(float v) {
#pragma unroll
  for (int m = 32; m >= 1; m >>= 1) v += __shfl_xor(v, m, 64);
  return v;
}
__device__ __forceinline__ void up8(U4 u, float* f) {
  f[0] = b2f(u.x & 0xffffu); f[1] = b2f(u.x >> 16);
  f[2] = b2f(u.y & 0xffffu); f[3] = b2f(u.y >> 16);
  f[4] = b2f(u.z & 0xffffu); f[5] = b2f(u.z >> 16);
  f[6] = b2f(u.w & 0xffffu); f[7] = b2f(u.w >> 16);
}

// ---------------- prep: U = h@We0[:64]+be0, V = h@We0[64:128]; bf16 transposed weight images ----------------
__global__ __launch_bounds__(64) void sake_prep(
    const float* __restrict__ h, const float* __restrict__ We0,
    const float* __restrict__ be0, const float* __restrict__ We1,
    const float* __restrict__ Wc0, const float* __restrict__ Wc1,
    const float* __restrict__ Wx0, const float* __restrict__ Ws,
    float* __restrict__ U, float* __restrict__ V, u16* __restrict__ WT)
{
  const int t = threadIdx.x;
  const int blk = blockIdx.x;
  if (blk < NROW) {
    __shared__ float hs[64];
    hs[t] = h[blk * 64 + t];
    __syncthreads();
    float u = be0[t], v = 0.f;
#pragma unroll 8
    for (int k = 0; k < 64; k++) {
      float hv = hs[k];
      u = fmaf(hv, We0[k * 64 + t], u);
      v = fmaf(hv, We0[(64 + k) * 64 + t], v);
    }
    U[blk * 64 + t] = u;
    V[blk * 64 + t] = v;
  } else {
    const int wsel = blk - NROW;
    if (wsel == 4) {
      u16* dst = WT + 14336;     // WsPT: 16x64, cols 4..15 zero
      for (int o = t; o < 16 * 64; o += 64) {
        int c = o >> 6, k = o & 63;
        dst[o] = (c < 4) ? f2b(Ws[k * 4 + c]) : (u16)0;
      }
      return;
    }
    const float* src; int nout; u16* dst;
    if      (wsel == 0) { src = We1; nout = 64; dst = WT;         }
    else if (wsel == 1) { src = Wc0; nout = 64; dst = WT + 4096;  }
    else if (wsel == 2) { src = Wx0; nout = 64; dst = WT + 8192;  }
    else                { src = Wc1; nout = 32; dst = WT + 12288; }
    const int total = 64 * nout;
    for (int o = t; o < total; o += 64) {
      int n = o >> 6, k = o & 63;
      dst[o] = f2b(src[k * nout + n]);
    }
  }
}

// ---------------- main: one block per (row, j-tile) ----------------
struct MainArgs {
  const float *x, *U, *V;
  const u16 *We1T, *Wc0T, *Wx0T, *Wc1T, *WsPT;
  const float *We0, *bs, *be1, *bc0, *bc1, *bx0, *Wx1, *log_gamma;
  char* rec;
};

// 64x64 @ 64x64 GEMM, A from swizzled LDS tile, B from global [n][k] bf16 image; silu; swizzled bf16 out.
// wave w owns rows 16w..16w+15. Row swizzle: 16B chunk c of row r at chunk (c ^ (r&7)).
// DUALT also writes transposed oTT[col][row] with the same swizzle family.
template<bool DUALT>
__device__ __forceinline__ void gemm64(const u16* aT, const u16* __restrict__ wG,
                                       const float* bias, u16* oT, u16* oTT, int w, int lane)
{
  const int m0 = w << 4;
  const int arow = m0 + (lane & 15);
  const int r7 = arow & 7;
  const int kg = lane >> 4;
  bf16x8 a0 = *(const bf16x8*)(aT + arow * 64 + ((kg ^ r7) << 3));
  bf16x8 a1 = *(const bf16x8*)(aT + arow * 64 + ((((kg + 4)) ^ r7) << 3));
#pragma unroll
  for (int nt = 0; nt < 4; nt++) {
    const int col = (nt << 4) + (lane & 15);
    const u16* wrow = wG + col * 64;
    bf16x8 b0 = *(const bf16x8*)(wrow + (kg << 3));
    bf16x8 b1 = *(const bf16x8*)(wrow + 32 + (kg << 3));
    f32x4 acc = {0.f, 0.f, 0.f, 0.f};
    acc = __builtin_amdgcn_mfma_f32_16x16x32_bf16(a0, b0, acc, 0, 0, 0);
    acc = __builtin_amdgcn_mfma_f32_16x16x32_bf16(a1, b1, acc, 0, 0, 0);
    const float bv = bias[col];
    const int cs = col >> 3, ce = col & 7;
#pragma unroll
    for (int r = 0; r < 4; r++) {
      const int row = m0 + (kg << 2) + r;
      const u16 v = f2b(silu_f(acc[r] + bv));
      oT[row * 64 + ((cs ^ (row & 7)) << 3) + ce] = v;
      if constexpr (DUALT)
        oTT[col * 64 + ((((row >> 3)) ^ (col & 7)) << 3) + (row & 7)] = v;
    }
  }
}

__global__ __launch_bounds__(256, 5) void sake_main(MainArgs A)
{
  __shared__ __align__(16) u16 buf0[64 * 64];   // h1 / c1 / s1
  __shared__ __align__(16) u16 hes[64 * 64];    // h_e row-swz; then cA/xA f32 scratch
  __shared__ __align__(16) u16 hesT[64 * 64];   // h_e transposed swz
  __shared__ __align__(16) u16 reg3[64 * 32];   // coeff (stride 32); then E tile at +1024 u16
  __shared__ float raw_lds[64 * 5];             // sem logits [j][head]
  __shared__ float disp[64][3];
  __shared__ float nrm_s[64];
  __shared__ float sU[64], wd[64], sbe1[64], sbc0[64], sbx0[64], sWx1[64];
  __shared__ float sbc1[32], sbs[4], sgam[4];

  const int t = threadIdx.x;
  const int w = t >> 6, lane = t & 63;
  const int bt = blockIdx.x;
  const int i = bt % NPT;
  const int bj = bt / NPT;          // b*NT + jt
  const int jt = bj % NT, b = bj / NT;
  const int bi = b * NPT + i;
  const int j0 = jt << 6;
  const int jj2 = t >> 2, q4 = t & 3;
  char* rec = A.rec + (size_t)(bi * NT + jt) * RECB;

  // issue independent global loads early
  const int j = j0 + jj2;
  const float* xp = &A.x[(b * NPT + j) * 3];
  const float xj0 = xp[0], xj1 = xp[1], xj2 = xp[2];
  const float xi0 = A.x[bi * 3 + 0], xi1 = A.x[bi * 3 + 1], xi2 = A.x[bi * 3 + 2];
  const float4* vp = (const float4*)(A.V + (size_t)(b * NPT + j) * 64 + q4 * 16);
  const float4 v0_ = vp[0], v1_ = vp[1], v2_ = vp[2], v3_ = vp[3];

  if (t < 64) {
    sU[t]   = A.U[bi * 64 + t];
    wd[t]   = A.We0[128 * 64 + t];
    sbe1[t] = A.be1[t];
    sbc0[t] = A.bc0[t];
    sbx0[t] = A.bx0[t];
    sWx1[t] = A.Wx1[t];
    if (t < 32) sbc1[t] = A.bc1[t];
    if (t < 4) { sbs[t] = A.bs[t]; sgam[t] = __expf(A.log_gamma[t]); }
  }
  __syncthreads();   // SYNC0: consts ready

  float cA0 = 0, cA1 = 0, cA2 = 0, xA0 = 0, xA1 = 0, xA2 = 0;

  // ---- stage h1 = silu(u_i + v_j + norm*wd), rows jj2 (wave-stripe-local) ----
  {
    float dx0 = xi0 - xj0, dx1 = xi1 - xj1, dx2 = xi2 - xj2;
    float nr = sqrtf(fmaf(dx0, dx0, fmaf(dx1, dx1, fmaf(dx2, dx2, kEPS))));
    if (q4 == 0) { disp[jj2][0] = dx0; disp[jj2][1] = dx1; disp[jj2][2] = dx2; nrm_s[jj2] = nr; }
    float vv[16] = {v0_.x, v0_.y, v0_.z, v0_.w, v1_.x, v1_.y, v1_.z, v1_.w,
                    v2_.x, v2_.y, v2_.z, v2_.w, v3_.x, v3_.y, v3_.z, v3_.w};
    float sv[16];
#pragma unroll
    for (int e = 0; e < 16; e++) {
      const int f = q4 * 16 + e;
      sv[e] = silu_f(sU[f] + vv[e] + nr * wd[f]);
    }
    U4 lo, hi;
    lo.x = pk2(sv[0], sv[1]);   lo.y = pk2(sv[2], sv[3]);
    lo.z = pk2(sv[4], sv[5]);   lo.w = pk2(sv[6], sv[7]);
    hi.x = pk2(sv[8], sv[9]);   hi.y = pk2(sv[10], sv[11]);
    hi.z = pk2(sv[12], sv[13]); hi.w = pk2(sv[14], sv[15]);
    const int r7 = jj2 & 7;
    *(U4*)(buf0 + jj2 * 64 + (((q4 * 2) ^ r7) << 3)) = lo;
    *(U4*)(buf0 + jj2 * 64 + (((q4 * 2 + 1) ^ r7) << 3)) = hi;
  }
  // ---- h_e = silu(h1 @ We1 + be1), dual write (all reads below are stripe-local until SYNC_B) ----
  gemm64<true>(buf0, A.We1T, sbe1, hes, hesT, w, lane);
  // ---- c1 = silu(h_e @ Wc0 + bc0) ----
  gemm64<false>(hes, A.Wc0T, sbc0, buf0, nullptr, w, lane);
  // ---- coeff = c1 @ Wc1 + bc1 (stride-32 bf16 in reg3) ----
  {
    const int m0 = w << 4;
    const int arow = m0 + (lane & 15);
    const int r7a = arow & 7;
    const int kg = lane >> 4;
    bf16x8 a0 = *(const bf16x8*)(buf0 + arow * 64 + ((kg ^ r7a) << 3));
    bf16x8 a1 = *(const bf16x8*)(buf0 + arow * 64 + (((kg + 4) ^ r7a) << 3));
#pragma unroll
    for (int nt = 0; nt < 2; nt++) {
      const int col = (nt << 4) + (lane & 15);
      const u16* wrow = A.Wc1T + col * 64;
      bf16x8 b0 = *(const bf16x8*)(wrow + (kg << 3));
      bf16x8 b1 = *(const bf16x8*)(wrow + 32 + (kg << 3));
      f32x4 acc = {0.f, 0.f, 0.f, 0.f};
      acc = __builtin_amdgcn_mfma_f32_16x16x32_bf16(a0, b0, acc, 0, 0, 0);
      acc = __builtin_amdgcn_mfma_f32_16x16x32_bf16(a1, b1, acc, 0, 0, 0);
      const float bv = sbc1[col];
#pragma unroll
      for (int r = 0; r < 4; r++) {
        const int row = m0 + (kg << 2) + r;
        reg3[row * 32 + col] = f2b(acc[r] + bv);
      }
    }
  }
  // ---- combinations partial: cA(c) += coeff/(nr+eps) * disp (stripe-local rows) ----
  {
    const int c = t & 31, g = t >> 5;
#pragma unroll
    for (int it = 0; it < 8; ++it) {
      const int jj = (g << 3) + it;
      const float s = b2f(reg3[jj * 32 + c]) * __builtin_amdgcn_rcpf(nrm_s[jj] + kEPS);
      cA0 = fmaf(s, disp[jj][0], cA0);
      cA1 = fmaf(s, disp[jj][1], cA1);
      cA2 = fmaf(s, disp[jj][2], cA2);
    }
  }
  // ---- s1 = silu(h_e @ Wx0 + bx0) ----
  gemm64<false>(hes, A.Wx0T, sbx0, buf0, nullptr, w, lane);
  // ---- scale = s1 @ Wx1 ; coordinate partial ----
  {
    const int jj = jj2;
    const int r7 = jj & 7;
    float acc = 0.f;
#pragma unroll
    for (int c2 = 0; c2 < 2; c2++) {
      const int c = q4 * 2 + c2;
      U4 u = *(const U4*)(buf0 + jj * 64 + ((c ^ r7) << 3));
      float f8[8]; up8(u, f8);
#pragma unroll
      for (int e = 0; e < 8; e++) acc = fmaf(f8[e], sWx1[c * 8 + e], acc);
    }
    acc += __shfl_xor(acc, 1, 64);
    acc += __shfl_xor(acc, 2, 64);
    if (q4 == 0) {
      xA0 = fmaf(disp[jj][0], acc, xA0);
      xA1 = fmaf(disp[jj][1], acc, xA1);
      xA2 = fmaf(disp[jj][2], acc, xA2);
    }
  }
  // ---- semantic logits via MFMA: raw[j][head] ----
  {
    const int m0 = w << 4;
    const int arow = m0 + (lane & 15);
    const int r7a = arow & 7;
    const int kg = lane >> 4;
    bf16x8 a0 = *(const bf16x8*)(hes + arow * 64 + ((kg ^ r7a) << 3));
    bf16x8 a1 = *(const bf16x8*)(hes + arow * 64 + (((kg + 4) ^ r7a) << 3));
    const u16* wrow = A.WsPT + (lane & 15) * 64;
    bf16x8 b0 = *(const bf16x8*)(wrow + (kg << 3));
    bf16x8 b1 = *(const bf16x8*)(wrow + 32 + (kg << 3));
    f32x4 acc = {0.f, 0.f, 0.f, 0.f};
    acc = __builtin_amdgcn_mfma_f32_16x16x32_bf16(a0, b0, acc, 0, 0, 0);
    acc = __builtin_amdgcn_mfma_f32_16x16x32_bf16(a1, b1, acc, 0, 0, 0);
    if ((lane & 15) < 4) {
#pragma unroll
      for (int r = 0; r < 4; r++)
        raw_lds[(m0 + (kg << 2) + r) * 5 + (lane & 15)] = acc[r];
    }
  }
  __syncthreads();   // SYNC_B: raw_lds, nrm_s, hes reads all complete

  // ---- stash cA/xA partials in hes region (dead now) ----
  float* cascr = (float*)hes;
  cascr[t * 3 + 0] = cA0; cascr[t * 3 + 1] = cA1; cascr[t * 3 + 2] = cA2;
  if (q4 == 0) {
    float* xs = (float*)hes + 768;
    xs[jj2 * 3 + 0] = xA0; xs[jj2 * 3 + 1] = xA1; xs[jj2 * 3 + 2] = xA2;
  }
  // ---- per-tile softmax stats (head = w, j = lane); E tile into reg3+1024 ----
  {
    const int jj = lane, head = w;
    float raw = raw_lds[jj * 5 + head] + sbs[head];
    float bsem = (raw > 0.f) ? raw : 0.2f * raw;
    const bool self = (j0 + jj) == i;
    if (self) bsem -= kINF;
    const float aeu = -(nrm_s[jj] + (self ? kINF : 0.f)) * sgam[head];
    const float L = aeu + bsem;
    const float mL = wredmax(L);
    const float eL = __expf(L - mL);
    const float SL = wredsum(eL);
    const float mb = wredmax(bsem);
    const float Sb = wredsum(__expf(bsem - mb));
    const float Sa = wredsum(__expf(aeu));
    u16* E = reg3 + 1024;
    E[head * 64 + (((jj >> 3) ^ head) << 3) + (jj & 7)] = f2b(eL);
    if (lane == 0) {
      float* sp = (float*)(rec + 908) + head * 5;
      sp[0] = mL; sp[1] = SL; sp[2] = mb; sp[3] = Sb; sp[4] = Sa;
    }
  }
  __syncthreads();   // SYNC_C: E tile + scratch ready

  // ---- A partial via MFMA: A[head][f] = sum_j eL * h_e[j][f] ----
  {
    const int kg = lane >> 4;
    const int erow = lane & 15;
    const int e7 = erow & 7;
    const u16* E = reg3 + 1024;
    bf16x8 ea0 = *(const bf16x8*)(E + erow * 64 + ((kg ^ e7) << 3));
    bf16x8 ea1 = *(const bf16x8*)(E + erow * 64 + (((kg + 4) ^ e7) << 3));
    const int f = (w << 4) + (lane & 15);
    const int f7 = f & 7;
    bf16x8 hb0 = *(const bf16x8*)(hesT + f * 64 + ((kg ^ f7) << 3));
    bf16x8 hb1 = *(const bf16x8*)(hesT + f * 64 + (((kg + 4) ^ f7) << 3));
    f32x4 aF = {0.f, 0.f, 0.f, 0.f};
    aF = __builtin_amdgcn_mfma_f32_16x16x32_bf16(ea0, hb0, aF, 0, 0, 0);
    aF = __builtin_amdgcn_mfma_f32_16x16x32_bf16(ea1, hb1, aF, 0, 0, 0);
    if (kg == 0) {
      u16* rA = (u16*)rec;
#pragma unroll
      for (int r = 0; r < 4; r++) rA[r * 64 + (w << 4) + (lane & 15)] = f2b(aF[r]);
    }
  }
  // ---- reduce cA/xA partials -> record ----
  if (t < 96) {
    const int c = t & 31, d = t >> 5;
    float s = 0.f;
#pragma unroll
    for (int g = 0; g < 8; g++) s += cascr[(g * 32 + c) * 3 + d];
    ((float*)(rec + 512))[d * 32 + c] = s;
  } else if (t < 99) {
    const int d = t - 96;
    float s = 0.f;
    for (int k = 0; k < 64; k++) s += ((float*)hes + 768)[k * 3 + d];
    ((float*)(rec + 896))[d] = s;
  }
}

// ---------------- merge: one block per row; softmax-merge + finalize MLPs ----------------
struct MergeArgs {
  const float *h, *x, *Wp0, *bp0, *Wp1, *bp1, *Wn0, *bn0, *Wn1, *bn1;
  const char* rec;
  float* out;
};

__global__ __launch_bounds__(256) void sake_merge(MergeArgs M)
{
  __shared__ float sc[NT][20];
  __shared__ float wAl[NT][4];
  __shared__ float coefh[4];
  __shared__ float node_in[384];
  __shared__ float cmv[96];
  __shared__ float nrm32[32];
  __shared__ float t0s[64];
  __shared__ float scr[256];

  const int t = threadIdx.x;
  const int bi = blockIdx.x;
  const char* rb = M.rec + (size_t)bi * NT * RECB;

  if (t < NT * 20) {
    const int tt = t / 20, k = t % 20;
    sc[tt][k] = ((const float*)(rb + tt * RECB + 908))[k];
  }
  if (t < 64) node_in[t] = M.h[bi * 64 + t];
  __syncthreads();
  if (t < 4) {
    const int hh = t;
    float mL = -1e30f, mb = -1e30f;
    for (int tt = 0; tt < NT; tt++) {
      mL = fmaxf(mL, sc[tt][hh * 5 + 0]);
      mb = fmaxf(mb, sc[tt][hh * 5 + 2]);
    }
    float SL = 0.f, Sb = 0.f, Sa = 0.f;
    for (int tt = 0; tt < NT; tt++) {
      const float wa = __expf(sc[tt][hh * 5 + 0] - mL);
      wAl[tt][hh] = wa;
      SL = fmaf(wa, sc[tt][hh * 5 + 1], SL);
      Sb = fmaf(__expf(sc[tt][hh * 5 + 2] - mb), sc[tt][hh * 5 + 3], Sb);
      Sa += sc[tt][hh * 5 + 4];
    }
    const float Ff = __expf(mL - mb);
    coefh[hh] = Ff / fmaf(SL, Ff, kEPS * Sa * Sb);
  }
  __syncthreads();
  {  // h_e_agg
    const int hh = t >> 6, f = t & 63;
    float s = 0.f;
#pragma unroll
    for (int tt = 0; tt < NT; tt++)
      s = fmaf(wAl[tt][hh], b2f(((const u16*)(rb + tt * RECB))[hh * 64 + f]), s);
    node_in[64 + hh * 64 + f] = s * coefh[hh];
  }
  if (t < 96) {
    float s = 0.f;
#pragma unroll
    for (int tt = 0; tt < NT; tt++) s += ((const float*)(rb + tt * RECB + 512))[t];
    cmv[t] = s * (1.f / 384.f);
  }
  if (t >= 128 && t < 131) {
    const int d = t - 128;
    float s = 0.f;
#pragma unroll
    for (int tt = 0; tt < NT; tt++) s += ((const float*)(rb + tt * RECB + 896))[d];
    M.out[HOFF + bi * 3 + d] = M.x[bi * 3 + d] + s * (1.f / 384.f);
  }
  __syncthreads();
  if (t < 32) {
    const float v0 = cmv[t], v1 = cmv[32 + t], v2 = cmv[64 + t];
    nrm32[t] = v0 * v0 + v1 * v1 + v2 * v2;
  }
  __syncthreads();
  if (t < 64) {
    float a = M.bp0[t];
    for (int c = 0; c < 32; c++) a = fmaf(nrm32[c], M.Wp0[c * 64 + t], a);
    t0s[t] = silu_f(a);
  }
  __syncthreads();
  if (t < 64) {
    float a = M.bp1[t];
    for (int k = 0; k < 64; k++) a = fmaf(t0s[k], M.Wp1[k * 64 + t], a);
    node_in[320 + t] = a;
  }
  __syncthreads();
  {
    const int f = t & 63, q = t >> 6;
    float a = 0.f;
    const int k0 = q * 96;
    for (int k = 0; k < 96; k++) a = fmaf(node_in[k0 + k], M.Wn0[(k0 + k) * 64 + f], a);
    scr[t] = a;
  }
  __syncthreads();
  if (t < 64) {
    const float s = scr[t] + scr[64 + t] + scr[128 + t] + scr[192 + t] + M.bn0[t];
    t0s[t] = silu_f(s);
  }
  __syncthreads();
  if (t < 64) {
    float a = M.bn1[t];
    for (int k = 0; k < 64; k++) a = fmaf(t0s[k], M.Wn1[k * 64 + t], a);
    M.out[bi * 64 + t] = M.h[bi * 64 + t] + a;
  }
}

extern "C" void kernel_launch(void* const* d_in, const int* in_sizes, int n_in,
                              void* d_out, int out_size, void* d_ws, size_t ws_size,
                              hipStream_t stream)
{
  (void)in_sizes; (void)n_in; (void)out_size; (void)ws_size;
  const float* h   = (const float*)d_in[0];
  const float* x   = (const float*)d_in[1];
  const float* We0 = (const float*)d_in[2];
  const float* be0 = (const float*)d_in[3];
  const float* We1 = (const float*)d_in[4];
  const float* be1 = (const float*)d_in[5];
  const float* Ws  = (const float*)d_in[6];
  const float* bs  = (const float*)d_in[7];
  const float* Wc0 = (const float*)d_in[8];
  const float* bc0 = (const float*)d_in[9];
  const float* Wc1 = (const float*)d_in[10];
  const float* bc1 = (const float*)d_in[11];
  const float* Wp0 = (const float*)d_in[12];
  const float* bp0 = (const float*)d_in[13];
  const float* Wp1 = (const float*)d_in[14];
  const float* bp1 = (const float*)d_in[15];
  const float* Wx0 = (const float*)d_in[16];
  const float* bx0 = (const float*)d_in[17];
  const float* Wx1 = (const float*)d_in[18];
  const float* Wn0 = (const float*)d_in[19];
  const float* bn0 = (const float*)d_in[20];
  const float* Wn1 = (const float*)d_in[21];
  const float* bn1 = (const float*)d_in[22];
  const float* lg  = (const float*)d_in[23];

  float* U = (float*)d_ws;
  float* V = U + NROW * 64;
  u16* WT = (u16*)(V + NROW * 64);
  char* rec = (char*)d_ws + REC_OFF;

  sake_prep<<<NROW + 5, 64, 0, stream>>>(h, We0, be0, We1, Wc0, Wc1, Wx0, Ws, U, V, WT);

  MainArgs A;
  A.x = x; A.U = U; A.V = V;
  A.We1T = WT; A.Wc0T = WT + 4096; A.Wx0T = WT + 8192; A.Wc1T = WT + 12288;
  A.WsPT = WT + 14336;
  A.We0 = We0; A.bs = bs; A.be1 = be1; A.bc0 = bc0; A.bc1 = bc1;
  A.bx0 = bx0; A.Wx1 = Wx1; A.log_gamma = lg;
  A.rec = rec;
  sake_main<<<NROW * NT, 256, 0, stream>>>(A);

  MergeArgs Mg;
  Mg.h = h; Mg.x = x;
  Mg.Wp0 = Wp0; Mg.bp0 = bp0; Mg.Wp1 = Wp1; Mg.bp1 = bp1;
  Mg.Wn0 = Wn0; Mg.bn0 = bn0; Mg.Wn1 = Wn1; Mg.bn1 = bn1;
  Mg.rec = rec; Mg.out = (float*)d_out;
  sake_merge<<<NROW, 256, 0, stream>>>(Mg);
}